// Round 1
// baseline (2038.358 us; speedup 1.0000x reference)
//
#include <hip/hip_runtime.h>
#include <hip/hip_bf16.h>
#include <cstdint>
#include <cstddef>

// Problem constants (reference: B=16, Adim=Bdim=512, E=256, An=Bn=2048)
#define BATCH 16
#define CDIM 512
#define EDIM 256
#define NDIM 2048

// ---------------------------------------------------------------------------
// gemm_wn: Y[b][m][n] = scale * sum_k W[m][k] * X[b][k][n]
//   W: [M][K] row-major (K contiguous), unbatched
//   X: [b][K][N] (N contiguous)
// Used for the three input projections (M=256,K=512) and W_out (M=512,K=256).
// ---------------------------------------------------------------------------
__global__ __launch_bounds__(256) void gemm_wn(
    const float* __restrict__ W, const float* __restrict__ X,
    float* __restrict__ Y, int M, int K, int N, float scale) {
  __shared__ alignas(16) float Ws[16][68];  // [k][m], 68-stride: 2-way max on stores
  __shared__ alignas(16) float Xs[16][64];  // [k][n]
  const int b = blockIdx.z;
  const int m0 = blockIdx.y * 64, n0 = blockIdx.x * 64;
  const float* __restrict__ Xb = X + (size_t)b * K * N;
  float* __restrict__ Yb = Y + (size_t)b * M * N;
  const int tid = threadIdx.x;
  const int tx = tid & 15, ty = tid >> 4;     // n-frag, m-frag
  const int wrow = tid >> 2, wk4 = tid & 3;   // W loader: 64 rows x 4 float4
  const int xk = tid >> 4, xn4 = tid & 15;    // X loader: 16 rows x 16 float4

  float4 acc[4];
  acc[0] = acc[1] = acc[2] = acc[3] = float4{0.f, 0.f, 0.f, 0.f};

  for (int k0 = 0; k0 < K; k0 += 16) {
    float4 wv = *(const float4*)&W[(size_t)(m0 + wrow) * K + k0 + wk4 * 4];
    Ws[wk4 * 4 + 0][wrow] = wv.x;
    Ws[wk4 * 4 + 1][wrow] = wv.y;
    Ws[wk4 * 4 + 2][wrow] = wv.z;
    Ws[wk4 * 4 + 3][wrow] = wv.w;
    *(float4*)&Xs[xk][xn4 * 4] =
        *(const float4*)&Xb[(size_t)(k0 + xk) * N + n0 + xn4 * 4];
    __syncthreads();
#pragma unroll
    for (int k = 0; k < 16; ++k) {
      float4 av = *(const float4*)&Ws[k][ty * 4];
      float4 bv = *(const float4*)&Xs[k][tx * 4];
      acc[0].x += av.x * bv.x; acc[0].y += av.x * bv.y; acc[0].z += av.x * bv.z; acc[0].w += av.x * bv.w;
      acc[1].x += av.y * bv.x; acc[1].y += av.y * bv.y; acc[1].z += av.y * bv.z; acc[1].w += av.y * bv.w;
      acc[2].x += av.z * bv.x; acc[2].y += av.z * bv.y; acc[2].z += av.z * bv.z; acc[2].w += av.z * bv.w;
      acc[3].x += av.w * bv.x; acc[3].y += av.w * bv.y; acc[3].z += av.w * bv.z; acc[3].w += av.w * bv.w;
    }
    __syncthreads();
  }
#pragma unroll
  for (int i = 0; i < 4; ++i) {
    float4 o = acc[i];
    o.x *= scale; o.y *= scale; o.z *= scale; o.w *= scale;
    *(float4*)&Yb[(size_t)(m0 + ty * 4 + i) * N + n0 + tx * 4] = o;
  }
}

// ---------------------------------------------------------------------------
// gemm_tn: Y[b][m][n] = scale * sum_k Ma[b][k][m] * Mb[b][k][n]
//   Both operands K-strided, m/n contiguous. Used for h = A^T * Bp / 16.
// ---------------------------------------------------------------------------
__global__ __launch_bounds__(256) void gemm_tn(
    const float* __restrict__ Ma, const float* __restrict__ Mb,
    float* __restrict__ Y, int M, int K, int N, float scale) {
  __shared__ alignas(16) float As[16][64];
  __shared__ alignas(16) float Bs[16][64];
  const int b = blockIdx.z;
  const int m0 = blockIdx.y * 64, n0 = blockIdx.x * 64;
  const float* __restrict__ Mab = Ma + (size_t)b * K * M;
  const float* __restrict__ Mbb = Mb + (size_t)b * K * N;
  float* __restrict__ Yb = Y + (size_t)b * M * N;
  const int tid = threadIdx.x;
  const int tx = tid & 15, ty = tid >> 4;
  const int lk = tid >> 4, l4 = tid & 15;

  float4 acc[4];
  acc[0] = acc[1] = acc[2] = acc[3] = float4{0.f, 0.f, 0.f, 0.f};

  for (int k0 = 0; k0 < K; k0 += 16) {
    *(float4*)&As[lk][l4 * 4] =
        *(const float4*)&Mab[(size_t)(k0 + lk) * M + m0 + l4 * 4];
    *(float4*)&Bs[lk][l4 * 4] =
        *(const float4*)&Mbb[(size_t)(k0 + lk) * N + n0 + l4 * 4];
    __syncthreads();
#pragma unroll
    for (int k = 0; k < 16; ++k) {
      float4 av = *(const float4*)&As[k][ty * 4];
      float4 bv = *(const float4*)&Bs[k][tx * 4];
      acc[0].x += av.x * bv.x; acc[0].y += av.x * bv.y; acc[0].z += av.x * bv.z; acc[0].w += av.x * bv.w;
      acc[1].x += av.y * bv.x; acc[1].y += av.y * bv.y; acc[1].z += av.y * bv.z; acc[1].w += av.y * bv.w;
      acc[2].x += av.z * bv.x; acc[2].y += av.z * bv.y; acc[2].z += av.z * bv.z; acc[2].w += av.z * bv.w;
      acc[3].x += av.w * bv.x; acc[3].y += av.w * bv.y; acc[3].z += av.w * bv.z; acc[3].w += av.w * bv.w;
    }
    __syncthreads();
  }
#pragma unroll
  for (int i = 0; i < 4; ++i) {
    float4 o = acc[i];
    o.x *= scale; o.y *= scale; o.z *= scale; o.w *= scale;
    *(float4*)&Yb[(size_t)(m0 + ty * 4 + i) * N + n0 + tx * 4] = o;
  }
}

// ---------------------------------------------------------------------------
// gemm_nt: Y[b][m][n] = sum_k Ma[b][m][k] * Mb[b][n][k]
//   Both operands K-contiguous. Used for out_e = Bh * att^T (K=2048).
// ---------------------------------------------------------------------------
__global__ __launch_bounds__(256) void gemm_nt(
    const float* __restrict__ Ma, const float* __restrict__ Mb,
    float* __restrict__ Y, int M, int K, int N) {
  __shared__ alignas(16) float Mas[16][68];  // [k][m], transposed on store
  __shared__ alignas(16) float Mbs[16][68];  // [k][n]
  const int b = blockIdx.z;
  const int m0 = blockIdx.y * 64, n0 = blockIdx.x * 64;
  const float* __restrict__ Mab = Ma + (size_t)b * M * K;
  const float* __restrict__ Mbb = Mb + (size_t)b * N * K;
  float* __restrict__ Yb = Y + (size_t)b * M * N;
  const int tid = threadIdx.x;
  const int tx = tid & 15, ty = tid >> 4;
  const int r = tid >> 2, k4 = tid & 3;  // 64 rows x 4 float4 along k

  float4 acc[4];
  acc[0] = acc[1] = acc[2] = acc[3] = float4{0.f, 0.f, 0.f, 0.f};

  for (int k0 = 0; k0 < K; k0 += 16) {
    float4 a = *(const float4*)&Mab[(size_t)(m0 + r) * K + k0 + k4 * 4];
    Mas[k4 * 4 + 0][r] = a.x;
    Mas[k4 * 4 + 1][r] = a.y;
    Mas[k4 * 4 + 2][r] = a.z;
    Mas[k4 * 4 + 3][r] = a.w;
    float4 c = *(const float4*)&Mbb[(size_t)(n0 + r) * K + k0 + k4 * 4];
    Mbs[k4 * 4 + 0][r] = c.x;
    Mbs[k4 * 4 + 1][r] = c.y;
    Mbs[k4 * 4 + 2][r] = c.z;
    Mbs[k4 * 4 + 3][r] = c.w;
    __syncthreads();
#pragma unroll
    for (int k = 0; k < 16; ++k) {
      float4 av = *(const float4*)&Mas[k][ty * 4];
      float4 bv = *(const float4*)&Mbs[k][tx * 4];
      acc[0].x += av.x * bv.x; acc[0].y += av.x * bv.y; acc[0].z += av.x * bv.z; acc[0].w += av.x * bv.w;
      acc[1].x += av.y * bv.x; acc[1].y += av.y * bv.y; acc[1].z += av.y * bv.z; acc[1].w += av.y * bv.w;
      acc[2].x += av.z * bv.x; acc[2].y += av.z * bv.y; acc[2].z += av.z * bv.z; acc[2].w += av.z * bv.w;
      acc[3].x += av.w * bv.x; acc[3].y += av.w * bv.y; acc[3].z += av.w * bv.z; acc[3].w += av.w * bv.w;
    }
    __syncthreads();
  }
#pragma unroll
  for (int i = 0; i < 4; ++i) {
    *(float4*)&Yb[(size_t)(m0 + ty * 4 + i) * N + n0 + tx * 4] = acc[i];
  }
}

// ---------------------------------------------------------------------------
// softmax_rows: in-place softmax over rows of length 2048 (att region).
// One block (256 threads) per row; 8 elements per thread.
// ---------------------------------------------------------------------------
__global__ __launch_bounds__(256) void softmax_rows(float* __restrict__ att) {
  float4* p = (float4*)(att + (size_t)blockIdx.x * NDIM);
  const int tid = threadIdx.x;
  float4 v0 = p[tid];
  float4 v1 = p[tid + 256];

  float m = fmaxf(fmaxf(fmaxf(v0.x, v0.y), fmaxf(v0.z, v0.w)),
                  fmaxf(fmaxf(v1.x, v1.y), fmaxf(v1.z, v1.w)));
#pragma unroll
  for (int off = 32; off; off >>= 1) m = fmaxf(m, __shfl_down(m, off));
  __shared__ float redm[4];
  if ((tid & 63) == 0) redm[tid >> 6] = m;
  __syncthreads();
  m = fmaxf(fmaxf(redm[0], redm[1]), fmaxf(redm[2], redm[3]));

  v0.x = __expf(v0.x - m); v0.y = __expf(v0.y - m);
  v0.z = __expf(v0.z - m); v0.w = __expf(v0.w - m);
  v1.x = __expf(v1.x - m); v1.y = __expf(v1.y - m);
  v1.z = __expf(v1.z - m); v1.w = __expf(v1.w - m);

  float s = v0.x + v0.y + v0.z + v0.w + v1.x + v1.y + v1.z + v1.w;
#pragma unroll
  for (int off = 32; off; off >>= 1) s += __shfl_down(s, off);
  __shared__ float reds[4];
  if ((tid & 63) == 0) reds[tid >> 6] = s;
  __syncthreads();
  s = reds[0] + reds[1] + reds[2] + reds[3];

  const float inv = 1.0f / s;
  v0.x *= inv; v0.y *= inv; v0.z *= inv; v0.w *= inv;
  v1.x *= inv; v1.y *= inv; v1.z *= inv; v1.w *= inv;
  p[tid] = v0;
  p[tid + 256] = v1;
}

// ---------------------------------------------------------------------------
// bn_stats: per-channel mean and rstd over (batch, positions): 16*2048 samples.
// One block per channel (512 blocks).
// ---------------------------------------------------------------------------
__global__ __launch_bounds__(256) void bn_stats(const float* __restrict__ o,
                                                float* __restrict__ mean,
                                                float* __restrict__ rstd) {
  const int c = blockIdx.x;
  const int tid = threadIdx.x;
  float s = 0.f, sq = 0.f;
  for (int b = 0; b < BATCH; ++b) {
    const float4* p = (const float4*)(o + ((size_t)b * CDIM + c) * NDIM);
    float4 v = p[tid];
    float4 w = p[tid + 256];
    s += v.x + v.y + v.z + v.w + w.x + w.y + w.z + w.w;
    sq += v.x * v.x + v.y * v.y + v.z * v.z + v.w * v.w +
          w.x * w.x + w.y * w.y + w.z * w.z + w.w * w.w;
  }
#pragma unroll
  for (int off = 32; off; off >>= 1) {
    s += __shfl_down(s, off);
    sq += __shfl_down(sq, off);
  }
  __shared__ float rs[4], rq[4];
  if ((tid & 63) == 0) { rs[tid >> 6] = s; rq[tid >> 6] = sq; }
  __syncthreads();
  if (tid == 0) {
    s = rs[0] + rs[1] + rs[2] + rs[3];
    sq = rq[0] + rq[1] + rq[2] + rq[3];
    const float invn = 1.0f / (BATCH * NDIM);
    float mu = s * invn;
    float var = sq * invn - mu * mu;
    mean[c] = mu;
    rstd[c] = rsqrtf(var + 1e-5f);
  }
}

// ---------------------------------------------------------------------------
// bn_norm: out = (out - mean[c]) * rstd[c] * gamma[c] + beta[c], in place.
// ---------------------------------------------------------------------------
__global__ __launch_bounds__(256) void bn_norm(float* __restrict__ o,
                                               const float* __restrict__ mean,
                                               const float* __restrict__ rstd,
                                               const float* __restrict__ gamma,
                                               const float* __restrict__ beta) {
  const size_t i = (size_t)blockIdx.x * 256 + threadIdx.x;  // float4 index
  const int c = (int)((i >> 9) & (CDIM - 1));               // 512 float4 per row
  float4 v = ((float4*)o)[i];
  const float a = rstd[c] * gamma[c];
  const float d = beta[c] - mean[c] * a;
  v.x = v.x * a + d; v.y = v.y * a + d;
  v.z = v.z * a + d; v.w = v.w * a + d;
  ((float4*)o)[i] = v;
}

// ---------------------------------------------------------------------------
extern "C" void kernel_launch(void* const* d_in, const int* in_sizes, int n_in,
                              void* d_out, int out_size, void* d_ws, size_t ws_size,
                              hipStream_t stream) {
  const float* input_A = (const float*)d_in[0];  // [16,512,2048]
  const float* input_B = (const float*)d_in[1];  // [16,512,2048]
  const float* W_A  = (const float*)d_in[2];     // [256,512]
  const float* W_B  = (const float*)d_in[3];     // [256,512]
  const float* W_Bh = (const float*)d_in[4];     // [256,512]
  const float* W_out = (const float*)d_in[5];    // [512,256]
  const float* gamma = (const float*)d_in[6];    // [512]
  const float* beta  = (const float*)d_in[7];    // [512]

  float* out = (float*)d_out;                       // [16,512,2048]
  float* att = out + (size_t)BATCH * CDIM * NDIM;   // [16,2048,2048]

  float* ws = (float*)d_ws;
  const size_t proj_elems = (size_t)BATCH * EDIM * NDIM;  // 8388608
  float* A    = ws;                   // [16,256,2048]
  float* Bp   = ws + proj_elems;      // [16,256,2048]
  float* Bh   = ws + 2 * proj_elems;  // [16,256,2048]
  float* oute = ws;                   // reuses A's slot (A dead after h)
  float* mean = ws + 3 * proj_elems;  // [512]
  float* rstd = mean + 512;           // [512]

  const dim3 blk(256);

  // Projections: [256x512] x [512x2048] per batch
  gemm_wn<<<dim3(32, 4, BATCH), blk, 0, stream>>>(W_A, input_A, A, EDIM, CDIM, NDIM, 1.0f);
  gemm_wn<<<dim3(32, 4, BATCH), blk, 0, stream>>>(W_B, input_B, Bp, EDIM, CDIM, NDIM, 1.0f);
  gemm_wn<<<dim3(32, 4, BATCH), blk, 0, stream>>>(W_Bh, input_B, Bh, EDIM, CDIM, NDIM, 1.0f);

  // h = A^T * Bp / sqrt(E): [2048x256] x [256x2048] per batch -> att region
  gemm_tn<<<dim3(32, 32, BATCH), blk, 0, stream>>>(A, Bp, att, NDIM, EDIM, NDIM, 0.0625f);

  // softmax over last dim, in place
  softmax_rows<<<dim3(BATCH * NDIM), blk, 0, stream>>>(att);

  // out_e = Bh * att^T: [256x2048] x [2048x2048]^T per batch
  gemm_nt<<<dim3(32, 4, BATCH), blk, 0, stream>>>(Bh, att, oute, EDIM, NDIM, NDIM);

  // out = W_out * out_e: [512x256] x [256x2048] per batch
  gemm_wn<<<dim3(32, 8, BATCH), blk, 0, stream>>>(W_out, oute, out, CDIM, EDIM, NDIM, 1.0f);

  // BatchNorm (training-mode batch stats), two-pass
  bn_stats<<<dim3(CDIM), blk, 0, stream>>>(out, mean, rstd);
  bn_norm<<<dim3(16384), blk, 0, stream>>>(out, mean, rstd, gamma, beta);
}

// Round 2
// 771.127 us; speedup vs baseline: 2.6433x; 2.6433x over previous
//
#include <hip/hip_runtime.h>
#include <cstdint>
#include <cstddef>

// Problem constants: B=16, Adim=Bdim=512(CDIM), E=256, An=Bn=2048(NDIM)
#define BATCH 16
#define CDIM 512
#define EDIM 256
#define NDIM 2048

typedef short bf16x8 __attribute__((ext_vector_type(8)));
typedef float f32x4 __attribute__((ext_vector_type(4)));

__device__ __forceinline__ unsigned short f2bf(float f) {
  union { float f; unsigned int u; } v; v.f = f;
  unsigned int r = v.u + 0x7fffu + ((v.u >> 16) & 1u);
  return (unsigned short)(r >> 16);
}

// ---------------------------------------------------------------------------
// cast_f32_bf16: flat f32 -> bf16 (for the weight matrices). n divisible by 1024.
// ---------------------------------------------------------------------------
__global__ __launch_bounds__(256) void cast_f32_bf16(const float* __restrict__ x,
                                                     unsigned short* __restrict__ y) {
  const int i = (blockIdx.x * 256 + threadIdx.x) * 4;
  float4 v = *(const float4*)&x[i];
  ushort4 o;
  o.x = f2bf(v.x); o.y = f2bf(v.y); o.z = f2bf(v.z); o.w = f2bf(v.w);
  *(ushort4*)&y[i] = o;
}

// ---------------------------------------------------------------------------
// transpose_cast: X f32 [b][CDIM][NDIM] -> Xt bf16 [b][NDIM][CDIM]
// 32x32 tiles via LDS. grid (NDIM/32, CDIM/32, BATCH), block 256.
// ---------------------------------------------------------------------------
__global__ __launch_bounds__(256) void transpose_cast(const float* __restrict__ X,
                                                      unsigned short* __restrict__ Xt) {
  __shared__ float tile[32][33];
  const int b = blockIdx.z;
  const float* Xb = X + (size_t)b * CDIM * NDIM;
  unsigned short* Xtb = Xt + (size_t)b * CDIM * NDIM;
  const int n0 = blockIdx.x * 32, c0 = blockIdx.y * 32;
  const int tx = threadIdx.x & 31, ty = threadIdx.x >> 5;
#pragma unroll
  for (int i = 0; i < 4; ++i)
    tile[ty + i * 8][tx] = Xb[(size_t)(c0 + ty + i * 8) * NDIM + n0 + tx];
  __syncthreads();
  const int nl = threadIdx.x >> 3, c4 = (threadIdx.x & 7) * 4;
  ushort4 o;
  o.x = f2bf(tile[c4 + 0][nl]); o.y = f2bf(tile[c4 + 1][nl]);
  o.z = f2bf(tile[c4 + 2][nl]); o.w = f2bf(tile[c4 + 3][nl]);
  *(ushort4*)&Xtb[(size_t)(n0 + nl) * CDIM + c0 + c4] = o;
}

// ---------------------------------------------------------------------------
// gemm_nt_mfma: C[b][m][n] = scale * sum_k A[b][m][k] * B[b][n][k]
//   A: bf16 [M][K] row-major (batch stride sA elems; 0 = broadcast)
//   B: bf16 or f32 [N][K] row-major (B_IS_F32 -> converted during staging)
//   C: OUT_F32 -> f32 [M][N]; OUT_BF16 -> bf16 [M][N]; OUT_BF16T -> bf16 [N][M]
// 128x128 tile, BK=64, 4 waves, each wave 64x64 = 4x4 of 16x16x32 MFMA.
// LDS rows padded to 72 shorts (144B): conflict-free b128 fragment reads.
// MFMA layouts (m89-verified): A-frag elem j = A[m=lane&15][k=(lane>>4)*8+j];
// B-frag elem j = B[k=(lane>>4)*8+j][n=lane&15]; D reg r = C[(lane>>4)*4+r][lane&15].
// ---------------------------------------------------------------------------
enum { OUT_F32 = 0, OUT_BF16 = 1, OUT_BF16T = 2 };

template <int OUTMODE, bool B_IS_F32>
__global__ __launch_bounds__(256) void gemm_nt_mfma(
    const void* __restrict__ Ap, const void* __restrict__ Bptr, void* __restrict__ Cp,
    int M, int N, int K, long sA, long sB, long sC, float scale) {
  __shared__ alignas(16) short As[128 * 72];
  __shared__ alignas(16) short Bs[128 * 72];
  const int b = blockIdx.z;
  const int m0 = blockIdx.y * 128, n0 = blockIdx.x * 128;
  const unsigned short* A = (const unsigned short*)Ap + (size_t)sA * b;
  const int tid = threadIdx.x;
  const int lane = tid & 63, wid = tid >> 6;
  const int l16 = lane & 15, q = lane >> 4;
  const int wm = (wid >> 1) * 64, wn = (wid & 1) * 64;
  const int sr = tid >> 1, sh = tid & 1;  // staging: row, half-row (64B each)

  f32x4 acc[4][4];
#pragma unroll
  for (int i = 0; i < 4; ++i)
#pragma unroll
    for (int j = 0; j < 4; ++j) acc[i][j] = f32x4{0.f, 0.f, 0.f, 0.f};

  short* a_dst = &As[sr * 72 + sh * 32];
  short* b_dst = &Bs[sr * 72 + sh * 32];

  for (int k0 = 0; k0 < K; k0 += 64) {
    {  // stage A tile: 128 rows x 64 bf16, 2 threads/row, 64B contiguous each
      const unsigned short* src = A + (size_t)(m0 + sr) * K + k0 + sh * 32;
      int4 c0 = *(const int4*)(src);
      int4 c1 = *(const int4*)(src + 8);
      int4 c2 = *(const int4*)(src + 16);
      int4 c3 = *(const int4*)(src + 24);
      *(int4*)(a_dst) = c0;
      *(int4*)(a_dst + 8) = c1;
      *(int4*)(a_dst + 16) = c2;
      *(int4*)(a_dst + 24) = c3;
    }
    if (B_IS_F32) {  // stage B tile with f32 -> bf16 conversion
      const float* src = (const float*)Bptr + (size_t)sB * b + (size_t)(n0 + sr) * K + k0 + sh * 32;
#pragma unroll
      for (int c = 0; c < 8; ++c) {
        float4 v = *(const float4*)(src + c * 4);
        ushort4 o;
        o.x = f2bf(v.x); o.y = f2bf(v.y); o.z = f2bf(v.z); o.w = f2bf(v.w);
        *(ushort4*)(b_dst + c * 4) = o;
      }
    } else {
      const unsigned short* src =
          (const unsigned short*)Bptr + (size_t)sB * b + (size_t)(n0 + sr) * K + k0 + sh * 32;
      int4 c0 = *(const int4*)(src);
      int4 c1 = *(const int4*)(src + 8);
      int4 c2 = *(const int4*)(src + 16);
      int4 c3 = *(const int4*)(src + 24);
      *(int4*)(b_dst) = c0;
      *(int4*)(b_dst + 8) = c1;
      *(int4*)(b_dst + 16) = c2;
      *(int4*)(b_dst + 24) = c3;
    }
    __syncthreads();
#pragma unroll
    for (int kk = 0; kk < 2; ++kk) {
      bf16x8 af[4], bfr[4];
#pragma unroll
      for (int t = 0; t < 4; ++t)
        af[t] = *(const bf16x8*)&As[(wm + t * 16 + l16) * 72 + kk * 32 + q * 8];
#pragma unroll
      for (int t = 0; t < 4; ++t)
        bfr[t] = *(const bf16x8*)&Bs[(wn + t * 16 + l16) * 72 + kk * 32 + q * 8];
#pragma unroll
      for (int i = 0; i < 4; ++i)
#pragma unroll
        for (int j = 0; j < 4; ++j)
          acc[i][j] = __builtin_amdgcn_mfma_f32_16x16x32_bf16(af[i], bfr[j], acc[i][j], 0, 0, 0);
    }
    __syncthreads();
  }

  const int mb = m0 + wm + q * 4, nb = n0 + wn + l16;
  if (OUTMODE == OUT_F32) {
    float* C = (float*)Cp + (size_t)sC * b;
#pragma unroll
    for (int i = 0; i < 4; ++i)
#pragma unroll
      for (int j = 0; j < 4; ++j)
#pragma unroll
        for (int r = 0; r < 4; ++r)
          C[(size_t)(mb + i * 16 + r) * N + nb + j * 16] = acc[i][j][r] * scale;
  } else if (OUTMODE == OUT_BF16) {
    unsigned short* C = (unsigned short*)Cp + (size_t)sC * b;
#pragma unroll
    for (int i = 0; i < 4; ++i)
#pragma unroll
      for (int j = 0; j < 4; ++j)
#pragma unroll
        for (int r = 0; r < 4; ++r)
          C[(size_t)(mb + i * 16 + r) * N + nb + j * 16] = f2bf(acc[i][j][r]);
  } else {  // OUT_BF16T: store C[m][n] at Ct[n][m]; 4 regs = 4 consecutive m
    unsigned short* C = (unsigned short*)Cp + (size_t)sC * b;
#pragma unroll
    for (int i = 0; i < 4; ++i)
#pragma unroll
      for (int j = 0; j < 4; ++j) {
        ushort4 o;
        o.x = f2bf(acc[i][j][0]); o.y = f2bf(acc[i][j][1]);
        o.z = f2bf(acc[i][j][2]); o.w = f2bf(acc[i][j][3]);
        *(ushort4*)&C[(size_t)(nb + j * 16) * M + mb + i * 16] = o;
      }
  }
}

// ---------------------------------------------------------------------------
// softmax_rows: in-place fp32 softmax over rows of length 2048 (att region).
// ---------------------------------------------------------------------------
__global__ __launch_bounds__(256) void softmax_rows(float* __restrict__ att) {
  float4* p = (float4*)(att + (size_t)blockIdx.x * NDIM);
  const int tid = threadIdx.x;
  float4 v0 = p[tid];
  float4 v1 = p[tid + 256];

  float m = fmaxf(fmaxf(fmaxf(v0.x, v0.y), fmaxf(v0.z, v0.w)),
                  fmaxf(fmaxf(v1.x, v1.y), fmaxf(v1.z, v1.w)));
#pragma unroll
  for (int off = 32; off; off >>= 1) m = fmaxf(m, __shfl_down(m, off));
  __shared__ float redm[4];
  if ((tid & 63) == 0) redm[tid >> 6] = m;
  __syncthreads();
  m = fmaxf(fmaxf(redm[0], redm[1]), fmaxf(redm[2], redm[3]));

  v0.x = __expf(v0.x - m); v0.y = __expf(v0.y - m);
  v0.z = __expf(v0.z - m); v0.w = __expf(v0.w - m);
  v1.x = __expf(v1.x - m); v1.y = __expf(v1.y - m);
  v1.z = __expf(v1.z - m); v1.w = __expf(v1.w - m);

  float s = v0.x + v0.y + v0.z + v0.w + v1.x + v1.y + v1.z + v1.w;
#pragma unroll
  for (int off = 32; off; off >>= 1) s += __shfl_down(s, off);
  __shared__ float reds[4];
  if ((tid & 63) == 0) reds[tid >> 6] = s;
  __syncthreads();
  s = reds[0] + reds[1] + reds[2] + reds[3];

  const float inv = 1.0f / s;
  v0.x *= inv; v0.y *= inv; v0.z *= inv; v0.w *= inv;
  v1.x *= inv; v1.y *= inv; v1.z *= inv; v1.w *= inv;
  p[tid] = v0;
  p[tid + 256] = v1;
}

// ---------------------------------------------------------------------------
// bn_stats / bn_norm: BatchNorm1d training-mode over (batch, positions).
// ---------------------------------------------------------------------------
__global__ __launch_bounds__(256) void bn_stats(const float* __restrict__ o,
                                                float* __restrict__ mean,
                                                float* __restrict__ rstd) {
  const int c = blockIdx.x;
  const int tid = threadIdx.x;
  float s = 0.f, sq = 0.f;
  for (int b = 0; b < BATCH; ++b) {
    const float4* p = (const float4*)(o + ((size_t)b * CDIM + c) * NDIM);
    float4 v = p[tid];
    float4 w = p[tid + 256];
    s += v.x + v.y + v.z + v.w + w.x + w.y + w.z + w.w;
    sq += v.x * v.x + v.y * v.y + v.z * v.z + v.w * v.w +
          w.x * w.x + w.y * w.y + w.z * w.z + w.w * w.w;
  }
#pragma unroll
  for (int off = 32; off; off >>= 1) {
    s += __shfl_down(s, off);
    sq += __shfl_down(sq, off);
  }
  __shared__ float rs[4], rq[4];
  if ((tid & 63) == 0) { rs[tid >> 6] = s; rq[tid >> 6] = sq; }
  __syncthreads();
  if (tid == 0) {
    s = rs[0] + rs[1] + rs[2] + rs[3];
    sq = rq[0] + rq[1] + rq[2] + rq[3];
    const float invn = 1.0f / (BATCH * NDIM);
    float mu = s * invn;
    float var = sq * invn - mu * mu;
    mean[c] = mu;
    rstd[c] = rsqrtf(var + 1e-5f);
  }
}

__global__ __launch_bounds__(256) void bn_norm(float* __restrict__ o,
                                               const float* __restrict__ mean,
                                               const float* __restrict__ rstd,
                                               const float* __restrict__ gamma,
                                               const float* __restrict__ beta) {
  const size_t i = (size_t)blockIdx.x * 256 + threadIdx.x;  // float4 index
  const int c = (int)((i >> 9) & (CDIM - 1));               // 512 float4 per row
  float4 v = ((float4*)o)[i];
  const float a = rstd[c] * gamma[c];
  const float d = beta[c] - mean[c] * a;
  v.x = v.x * a + d; v.y = v.y * a + d;
  v.z = v.z * a + d; v.w = v.w * a + d;
  ((float4*)o)[i] = v;
}

// ---------------------------------------------------------------------------
extern "C" void kernel_launch(void* const* d_in, const int* in_sizes, int n_in,
                              void* d_out, int out_size, void* d_ws, size_t ws_size,
                              hipStream_t stream) {
  const float* input_A = (const float*)d_in[0];  // [16,512,2048]
  const float* input_B = (const float*)d_in[1];  // [16,512,2048]
  const float* W_A   = (const float*)d_in[2];    // [256,512]
  const float* W_B   = (const float*)d_in[3];    // [256,512]
  const float* W_Bh  = (const float*)d_in[4];    // [256,512]
  const float* W_out = (const float*)d_in[5];    // [512,256]
  const float* gamma = (const float*)d_in[6];    // [512]
  const float* beta  = (const float*)d_in[7];    // [512]

  float* out = (float*)d_out;                      // [16,512,2048] f32
  float* att = out + (size_t)BATCH * CDIM * NDIM;  // [16,2048,2048] f32

  // Workspace layout (peak 84.9 MB < proven >=100.66 MB):
  char* w = (char*)d_ws;
  unsigned short* wA  = (unsigned short*)(w + 0);        // 256x512 bf16
  unsigned short* wB  = (unsigned short*)(w + 262144);
  unsigned short* wBh = (unsigned short*)(w + 524288);
  unsigned short* wO  = (unsigned short*)(w + 786432);   // 512x256 bf16
  float* mean = (float*)(w + 1048576);
  float* rstd = (float*)(w + 1050624);
  char* base = w + 1056768;
  unsigned short* X_At = (unsigned short*)(base);             // [16,2048,512] bf16, 33.55MB
  unsigned short* X_Bt = (unsigned short*)(base + 33554432);  // [16,2048,512] bf16
  unsigned short* A_t  = (unsigned short*)(base + 67108864);  // [16,2048,256] bf16
  unsigned short* Bp_t = (unsigned short*)(base);             // over dead X_At (1st half)
  unsigned short* Bh   = (unsigned short*)(base + 16777216);  // over dead X_At (2nd half)
  unsigned short* oute = (unsigned short*)(base + 67108864);  // over dead A_t: [16,2048,256]

  const dim3 blk(256);

  // Weight casts (131072 elems each = 128 blocks x 1024)
  cast_f32_bf16<<<dim3(128), blk, 0, stream>>>(W_A, wA);
  cast_f32_bf16<<<dim3(128), blk, 0, stream>>>(W_B, wB);
  cast_f32_bf16<<<dim3(128), blk, 0, stream>>>(W_Bh, wBh);
  cast_f32_bf16<<<dim3(128), blk, 0, stream>>>(W_out, wO);

  // Input transpose+cast: [b][512][2048] f32 -> [b][2048][512] bf16
  transpose_cast<<<dim3(64, 16, BATCH), blk, 0, stream>>>(input_A, X_At);
  transpose_cast<<<dim3(64, 16, BATCH), blk, 0, stream>>>(input_B, X_Bt);

  // G1a: A_t[a][e] = sum_c X_At[a][c] * W_A[e][c]   (M=2048,N=256,K=512)
  gemm_nt_mfma<OUT_BF16, false><<<dim3(2, 16, BATCH), blk, 0, stream>>>(
      X_At, wA, A_t, 2048, 256, 512, 1048576, 0, 524288, 1.f);
  // G1b: Bp_t[m][e] = sum_c X_Bt[m][c] * W_B[e][c]  (writes over dead X_At)
  gemm_nt_mfma<OUT_BF16, false><<<dim3(2, 16, BATCH), blk, 0, stream>>>(
      X_Bt, wB, Bp_t, 2048, 256, 512, 1048576, 0, 524288, 1.f);
  // G2: Bh[e][m] = sum_c W_Bh[e][c] * X_Bt[m][c]    (M=256,N=2048,K=512)
  gemm_nt_mfma<OUT_BF16, false><<<dim3(16, 2, BATCH), blk, 0, stream>>>(
      wBh, X_Bt, Bh, 256, 2048, 512, 0, 1048576, 524288, 1.f);
  // G3: h[a][m] = (1/16) sum_e A_t[a][e] * Bp_t[m][e] -> att region, f32
  gemm_nt_mfma<OUT_F32, false><<<dim3(16, 16, BATCH), blk, 0, stream>>>(
      A_t, Bp_t, att, 2048, 2048, 256, 524288, 524288, 4194304, 0.0625f);

  // softmax over last dim, fp32 in place
  softmax_rows<<<dim3(BATCH * NDIM), blk, 0, stream>>>(att);

  // G4: oute_t[a][e] = sum_m Bh[e][m] * att[a][m]  (B=att f32, converted in staging;
  //     transposed bf16 epilogue). M=256, N=2048, K=2048.
  gemm_nt_mfma<OUT_BF16T, true><<<dim3(16, 2, BATCH), blk, 0, stream>>>(
      Bh, att, oute, 256, 2048, 2048, 524288, 4194304, 524288, 1.f);

  // G5: out[c][a] = sum_e W_out[c][e] * oute_t[a][e]  (M=512,N=2048,K=256) -> f32
  gemm_nt_mfma<OUT_F32, false><<<dim3(16, 4, BATCH), blk, 0, stream>>>(
      wO, oute, out, 512, 2048, 256, 0, 524288, 1048576, 1.f);

  // BatchNorm (training-mode batch stats), two-pass
  bn_stats<<<dim3(CDIM), blk, 0, stream>>>(out, mean, rstd);
  bn_norm<<<dim3(16384), blk, 0, stream>>>(out, mean, rstd, gamma, beta);
}